// Round 8
// baseline (614.007 us; speedup 1.0000x reference)
//
#include <hip/hip_runtime.h>

// MicrotubuleDynamicsModel fused forward, round 8:
// Round-6 dataflow (x state = split bf16 pair in regs, aggregate-after-multiply,
// quad-transposed fp32 h-mirror for the sparse gather) with:
//  - feature-halved 16-plane LDS buffer (13.6KB) -> 8 blocks/CU, 16 waves
//  - hazard-free deferred schedule: all mm phases consume old x before any
//    state update (held accs for the second half, 4 barriers/layer)
//  - encoder D->B state conversion fully in-register via v_permlane32_swap_b32
//    (D rows {4hi+0..3,4hi+8..11} <-> B rows {8hi..8hi+7} exchange)

typedef __attribute__((ext_vector_type(2)))  float  f32x2;
typedef __attribute__((ext_vector_type(4)))  float  f32x4;
typedef __attribute__((ext_vector_type(16))) float  f32x16;
typedef __attribute__((ext_vector_type(8)))  __bf16 bf16x8;
typedef __attribute__((ext_vector_type(4)))  unsigned int u32x4;

#define MFMA(a, b, c) __builtin_amdgcn_mfma_f32_32x32x16_bf16((a), (b), (c), 0, 0, 0)

#define QSTR 53          // node slots per quad-plane (52 + 1 pad)
#define QP   (QSTR * 4)  // dwords per quad-plane = 212

struct bfpair { __bf16 h, l; };
__device__ __forceinline__ bfpair splitf(float f) {
    bfpair p;
    p.h = (__bf16)f;               // RTN
    p.l = (__bf16)(f - (float)p.h);
    return p;
}
__device__ __forceinline__ unsigned pk2(__bf16 a, __bf16 b) {
    return (unsigned)__builtin_bit_cast(unsigned short, a)
         | ((unsigned)__builtin_bit_cast(unsigned short, b) << 16);
}

// D-layout k-chunk (regs RB..RB+7 of a 32x32 D tile) -> B-frag split pair.
// Per lane-half exchange done by v_permlane32_swap_b32 (swaps vdst's high
// 32 lanes with src's low 32 lanes): (a0,b0) -> (word0, word2) for all lanes.
template<int RB>
__device__ __forceinline__ void d2b8(const f32x16 &v, bf16x8 &BH, bf16x8 &BL) {
    __bf16 h[8], l[8];
    #pragma unroll
    for (int i = 0; i < 8; ++i) { bfpair p = splitf(v[RB + i]); h[i] = p.h; l[i] = p.l; }
    unsigned ha0 = pk2(h[0], h[1]), ha1 = pk2(h[2], h[3]);
    unsigned hb0 = pk2(h[4], h[5]), hb1 = pk2(h[6], h[7]);
    unsigned la0 = pk2(l[0], l[1]), la1 = pk2(l[2], l[3]);
    unsigned lb0 = pk2(l[4], l[5]), lb1 = pk2(l[6], l[7]);
    asm("v_permlane32_swap_b32 %0, %1" : "+v"(ha0), "+v"(hb0));
    asm("v_permlane32_swap_b32 %0, %1" : "+v"(la0), "+v"(lb0));
    asm("v_permlane32_swap_b32 %0, %1" : "+v"(ha1), "+v"(hb1));
    asm("v_permlane32_swap_b32 %0, %1" : "+v"(la1), "+v"(lb1));
    u32x4 uh = { ha0, ha1, hb0, hb1 };
    u32x4 ul = { la0, la1, lb0, lb1 };
    BH = __builtin_bit_cast(bf16x8, uh);
    BL = __builtin_bit_cast(bf16x8, ul);
}

// ---------------- prep: split + fragment-pack W into workspace ----------------
// frag tid = (((L*8+kc)*4+ot)*2+hi)*32+lane ; elems = W[L][ot*32+lane][kc*16+hi*8+e]
__global__ __launch_bounds__(256) void prep_w(
    const float* __restrict__ Wg, const float* __restrict__ Wd1,
    __bf16* __restrict__ ws)
{
    const int tid  = blockIdx.x * 256 + threadIdx.x;   // 0..8191
    const int lane = tid & 31;
    const int hi   = (tid >> 5) & 1;
    const int ot   = (tid >> 6) & 3;
    const int kc   = (tid >> 8) & 7;
    const int L    = tid >> 11;
    const float* src = ((L < 3) ? (Wg + L * 16384) : Wd1)
                     + (ot * 32 + lane) * 128 + kc * 16 + hi * 8;
    const f32x4 v0 = *(const f32x4*)(src);
    const f32x4 v1 = *(const f32x4*)(src + 4);
    bf16x8 h8, l8;
    #pragma unroll
    for (int e = 0; e < 4; ++e) {
        bfpair p0 = splitf(v0[e]); h8[e]   = p0.h; l8[e]   = p0.l;
        bfpair p1 = splitf(v1[e]); h8[4+e] = p1.h; l8[4+e] = p1.l;
    }
    ((bf16x8*)ws)[tid]        = h8;   // Ph
    ((bf16x8*)ws)[8192 + tid] = l8;   // Pl
}

// ------------------------------- main kernel -------------------------------
__global__ __launch_bounds__(128, 4) void mt_fwd(
    const float* __restrict__ q,   const float* __restrict__ Win, const float* __restrict__ bin,
    const float* __restrict__ bg,  const float* __restrict__ bd1,
    const float* __restrict__ Wd2, const float* __restrict__ bd2,
    const bf16x8* __restrict__ Ph, float* __restrict__ out)
{
    __shared__ __attribute__((aligned(16))) float hb[16 * QP];   // 13568 B

    const int t    = threadIdx.x;
    const int nt   = t >> 6;            // wave: node-tile 0/1
    const int l    = t & 63;
    const int lane = l & 31;
    const int hi   = l >> 5;
    const int n    = nt * 32 + lane;    // this lane's node (col in D)
    const int nc   = (n < 52) ? n : 0;
    const int samp = blockIdx.x;
    const bf16x8* Pl = Ph + 8192;

    const int wq = n * 4;    // own node dword offset within a plane (write)
    const int rq = nc * 4;   // clamped (read own)

    // ---- closed-form GCN neighbors (self + 2 lateral(dup x2) + <=2 chain) ----
    int nb[5]; float nw[5];
    {
        const int   fi = n >> 2, js = n & 3;
        const float dg = 5.f + (js > 0 ? 1.f : 0.f) + (js < 3 ? 1.f : 0.f);
        const float di = rsqrtf(dg);
        nb[0] = n;                          nw[0] = di * di;
        nb[1] = ((fi + 12) % 13) * 4 + js;  nw[1] = 2.f * di * di;
        nb[2] = ((fi + 1) % 13) * 4 + js;   nw[2] = 2.f * di * di;
        nb[3] = (js > 0) ? (n - 1) : 0;
        nw[3] = (js > 0) ? di * rsqrtf(6.f + (js > 1 ? 1.f : 0.f)) : 0.f;
        nb[4] = (js < 3) ? (n + 1) : 0;
        nw[4] = (js < 3) ? di * rsqrtf(6.f + (js < 2 ? 1.f : 0.f)) : 0.f;
        if (n >= 52) {
            #pragma unroll
            for (int c = 0; c < 5; ++c) { nb[c] = 0; nw[c] = 0.f; }
        }
    }
    int gq[5];
    #pragma unroll
    for (int c = 0; c < 5; ++c) gq[c] = nb[c] * 4;

    bf16x8 bh[8], bl[8];   // persistent x state (B-frag layout, split)

    // ---------------- encoder: x0 = relu(Win @ q^T + bin), in-reg conversion ----------------
    {
        f32x4 z4; z4[0]=0.f; z4[1]=0.f; z4[2]=0.f; z4[3]=0.f;
        f32x4 u0 = z4, u1 = z4;
        if (hi == 0 && n < 52) {
            const float* qp = q + (samp * 52 + n) * 6;
            const f32x2 a = *(const f32x2*)(qp);
            const f32x2 b = *(const f32x2*)(qp + 2);
            const f32x2 c = *(const f32x2*)(qp + 4);
            u0[0]=a[0]; u0[1]=a[1]; u0[2]=b[0]; u0[3]=b[1]; u1[0]=c[0]; u1[1]=c[1];
        }
        bf16x8 qh, ql;
        #pragma unroll
        for (int e = 0; e < 4; ++e) {
            bfpair p0 = splitf(u0[e]); qh[e]   = p0.h; ql[e]   = p0.l;
            bfpair p1 = splitf(u1[e]); qh[4+e] = p1.h; ql[4+e] = p1.l;
        }

        #pragma unroll
        for (int ot = 0; ot < 4; ++ot) {
            f32x4 v0 = z4, v1 = z4;
            if (hi == 0) {
                const int o_r = ot * 32 + lane;
                const f32x2 a = *(const f32x2*)(Win + o_r * 6);
                const f32x2 b = *(const f32x2*)(Win + o_r * 6 + 2);
                const f32x2 c = *(const f32x2*)(Win + o_r * 6 + 4);
                v0[0]=a[0]; v0[1]=a[1]; v0[2]=b[0]; v0[3]=b[1]; v1[0]=c[0]; v1[1]=c[1];
            }
            bf16x8 ah, al;
            #pragma unroll
            for (int e = 0; e < 4; ++e) {
                bfpair p0 = splitf(v0[e]); ah[e]   = p0.h; al[e]   = p0.l;
                bfpair p1 = splitf(v1[e]); ah[4+e] = p1.h; al[4+e] = p1.l;
            }
            f32x16 acc;
            #pragma unroll
            for (int r = 0; r < 16; ++r) acc[r] = 0.f;
            acc = MFMA(ah, qh, acc);
            acc = MFMA(ah, ql, acc);
            acc = MFMA(al, qh, acc);
            // epilogue in regs
            f32x16 v;
            #pragma unroll
            for (int j = 0; j < 4; ++j) {
                const f32x4 bv = *(const f32x4*)(bin + ot * 32 + 8 * j + 4 * hi);
                #pragma unroll
                for (int e = 0; e < 4; ++e) v[4 * j + e] = fmaxf(acc[4 * j + e] + bv[e], 0.f);
            }
            d2b8<0>(v, bh[2 * ot],     bl[2 * ot]);
            d2b8<8>(v, bh[2 * ot + 1], bl[2 * ot + 1]);
        }
    }

    // helpers -----------------------------------------------------------------
    auto mmtile = [&](int fbase, int ot) {
        f32x16 acc;
        #pragma unroll
        for (int r = 0; r < 16; ++r) acc[r] = 0.f;
        #pragma unroll
        for (int kc = 0; kc < 8; ++kc) {
            const int fk = fbase + kc * 256 + ot * 64;
            const bf16x8 wh = Ph[fk];
            const bf16x8 wl = Pl[fk];
            acc = MFMA(wh, bh[kc], acc);
            acc = MFMA(wh, bl[kc], acc);
            acc = MFMA(wl, bh[kc], acc);
        }
        return acc;
    };
    auto wrplanes = [&](const f32x16 &acc, int ot) {
        if (n < 52) {
            #pragma unroll
            for (int j = 0; j < 4; ++j) {
                f32x4 v = { acc[4*j+0], acc[4*j+1], acc[4*j+2], acc[4*j+3] };
                *(f32x4*)&hb[((ot & 1) * 8 + 2 * j + hi) * QP + wq] = v;
            }
        }
    };
    auto wrplanesRelu = [&](const f32x16 &acc, int ot, const float* bsrc) {
        if (n < 52) {
            #pragma unroll
            for (int j = 0; j < 4; ++j) {
                const f32x4 bv = *(const f32x4*)(bsrc + ot * 32 + 8 * j + 4 * hi);
                f32x4 v;
                #pragma unroll
                for (int e = 0; e < 4; ++e) v[e] = fmaxf(acc[4 * j + e] + bv[e], 0.f);
                *(f32x4*)&hb[((ot & 1) * 8 + 2 * j + hi) * QP + wq] = v;
            }
        }
    };

    // ------------------- 3 GNN layers (deferred-update schedule) -------------------
    #pragma unroll 1
    for (int L = 0; L < 3; ++L) {
        const int fbase = L * 2048 + hi * 32 + lane;
        const float* bsrc = bg + L * 128;

        // mmA: ot 0,1 -> write planes
        {
            f32x16 a0 = mmtile(fbase, 0); wrplanes(a0, 0);
            f32x16 a1 = mmtile(fbase, 1); wrplanes(a1, 1);
        }
        __syncthreads();                         // bar1: half-A planes visible

        // mmB: ot 2,3 held in regs (old x fully consumed after this)
        f32x16 a2 = mmtile(fbase, 2);
        f32x16 a3 = mmtile(fbase, 3);

        // gatherA: kc 0..3, update state in place (old x dead)
        #pragma unroll
        for (int kc = 0; kc < 4; ++kc) {
            const int p0 = ((kc >> 1) & 1) * 8 + (kc & 1) * 4 + 2 * hi;
            f32x4 t0, t1;
            #pragma unroll
            for (int e = 0; e < 4; ++e) { t0[e] = 0.f; t1[e] = 0.f; }
            #pragma unroll
            for (int c = 0; c < 5; ++c) {
                t0 += nw[c] * *(const f32x4*)&hb[p0 * QP + gq[c]];
                t1 += nw[c] * *(const f32x4*)&hb[(p0 + 1) * QP + gq[c]];
            }
            const f32x4 b0 = *(const f32x4*)(bsrc + kc * 16 + 8 * hi);
            const f32x4 b1 = *(const f32x4*)(bsrc + kc * 16 + 8 * hi + 4);
            #pragma unroll
            for (int e = 0; e < 4; ++e) {
                {
                    const float xo = (float)bh[kc][e] + (float)bl[kc][e];
                    const float xn = xo + fmaxf(t0[e] + b0[e], 0.f);
                    bfpair p = splitf(xn); bh[kc][e] = p.h; bl[kc][e] = p.l;
                }
                {
                    const float xo = (float)bh[kc][4+e] + (float)bl[kc][4+e];
                    const float xn = xo + fmaxf(t1[e] + b1[e], 0.f);
                    bfpair p = splitf(xn); bh[kc][4+e] = p.h; bl[kc][4+e] = p.l;
                }
            }
        }
        __syncthreads();                         // bar2: gatherA reads done

        wrplanes(a2, 2);
        wrplanes(a3, 3);
        __syncthreads();                         // bar3: half-B planes visible

        // gatherB: kc 4..7
        #pragma unroll
        for (int kc = 4; kc < 8; ++kc) {
            const int p0 = ((kc >> 1) & 1) * 8 + (kc & 1) * 4 + 2 * hi;
            f32x4 t0, t1;
            #pragma unroll
            for (int e = 0; e < 4; ++e) { t0[e] = 0.f; t1[e] = 0.f; }
            #pragma unroll
            for (int c = 0; c < 5; ++c) {
                t0 += nw[c] * *(const f32x4*)&hb[p0 * QP + gq[c]];
                t1 += nw[c] * *(const f32x4*)&hb[(p0 + 1) * QP + gq[c]];
            }
            const f32x4 b0 = *(const f32x4*)(bsrc + kc * 16 + 8 * hi);
            const f32x4 b1 = *(const f32x4*)(bsrc + kc * 16 + 8 * hi + 4);
            #pragma unroll
            for (int e = 0; e < 4; ++e) {
                {
                    const float xo = (float)bh[kc][e] + (float)bl[kc][e];
                    const float xn = xo + fmaxf(t0[e] + b0[e], 0.f);
                    bfpair p = splitf(xn); bh[kc][e] = p.h; bl[kc][e] = p.l;
                }
                {
                    const float xo = (float)bh[kc][4+e] + (float)bl[kc][4+e];
                    const float xn = xo + fmaxf(t1[e] + b1[e], 0.f);
                    bfpair p = splitf(xn); bh[kc][4+e] = p.h; bl[kc][4+e] = p.l;
                }
            }
        }
        __syncthreads();                         // bar4: gatherB reads done
    }

    // ---------------- decoder-1: y = relu(x @ Wd1^T + bd1), parked halves ----------------
    {
        const int fbase = 3 * 2048 + hi * 32 + lane;
        {
            f32x16 a0 = mmtile(fbase, 0); wrplanesRelu(a0, 0, bd1);
            f32x16 a1 = mmtile(fbase, 1); wrplanesRelu(a1, 1, bd1);
        }
        __syncthreads();
        f32x16 a2 = mmtile(fbase, 2);
        f32x16 a3 = mmtile(fbase, 3);                // old x fully consumed
        // readback kc 0..3 (own node)
        #pragma unroll
        for (int kc = 0; kc < 4; ++kc) {
            const int p0 = ((kc >> 1) & 1) * 8 + (kc & 1) * 4 + 2 * hi;
            const f32x4 a0r = *(const f32x4*)&hb[p0 * QP + rq];
            const f32x4 a1r = *(const f32x4*)&hb[(p0 + 1) * QP + rq];
            #pragma unroll
            for (int e = 0; e < 4; ++e) {
                bfpair q0 = splitf(a0r[e]); bh[kc][e]   = q0.h; bl[kc][e]   = q0.l;
                bfpair q1 = splitf(a1r[e]); bh[kc][4+e] = q1.h; bl[kc][4+e] = q1.l;
            }
        }
        __syncthreads();
        wrplanesRelu(a2, 2, bd1);
        wrplanesRelu(a3, 3, bd1);
        __syncthreads();
        #pragma unroll
        for (int kc = 4; kc < 8; ++kc) {
            const int p0 = ((kc >> 1) & 1) * 8 + (kc & 1) * 4 + 2 * hi;
            const f32x4 a0r = *(const f32x4*)&hb[p0 * QP + rq];
            const f32x4 a1r = *(const f32x4*)&hb[(p0 + 1) * QP + rq];
            #pragma unroll
            for (int e = 0; e < 4; ++e) {
                bfpair q0 = splitf(a0r[e]); bh[kc][e]   = q0.h; bl[kc][e]   = q0.l;
                bfpair q1 = splitf(a1r[e]); bh[kc][4+e] = q1.h; bl[kc][4+e] = q1.l;
            }
        }
    }

    // ---------------- decoder-2: out^T = Wd2 @ y^T + bd2 ----------------
    {
        f32x16 acc;
        #pragma unroll
        for (int r = 0; r < 16; ++r) acc[r] = 0.f;
        f32x4 z4; z4[0]=0.f; z4[1]=0.f; z4[2]=0.f; z4[3]=0.f;

        #pragma unroll
        for (int kc = 0; kc < 8; ++kc) {
            const int kb = kc * 16 + 8 * hi;
            f32x4 w0 = z4, w1 = z4;
            if (lane < 6) {
                const float* wp = Wd2 + lane * 128 + kb;
                w0 = *(const f32x4*)(wp);
                w1 = *(const f32x4*)(wp + 4);
            }
            bf16x8 ah, al;
            #pragma unroll
            for (int e = 0; e < 4; ++e) {
                bfpair p0 = splitf(w0[e]); ah[e]   = p0.h; al[e]   = p0.l;
                bfpair p1 = splitf(w1[e]); ah[4+e] = p1.h; al[4+e] = p1.l;
            }
            acc = MFMA(ah, bh[kc], acc);
            acc = MFMA(ah, bl[kc], acc);
            acc = MFMA(al, bh[kc], acc);
        }
        if (n < 52) {
            float* op = out + (samp * 52 + n) * 6;
            if (hi == 0) {
                #pragma unroll
                for (int r = 0; r < 4; ++r) op[r] = acc[r] + bd2[r];          // f = r
            } else {
                #pragma unroll
                for (int r = 0; r < 2; ++r) op[4 + r] = acc[r] + bd2[4 + r];  // f = 4+r
            }
        }
    }
}

extern "C" void kernel_launch(void* const* d_in, const int* in_sizes, int n_in,
                              void* d_out, int out_size, void* d_ws, size_t ws_size,
                              hipStream_t stream) {
    (void)in_sizes; (void)n_in; (void)ws_size; (void)out_size;
    const float* q   = (const float*)d_in[0];
    const float* Win = (const float*)d_in[1];
    const float* bin = (const float*)d_in[2];
    const float* Wg  = (const float*)d_in[3];
    const float* bg  = (const float*)d_in[4];
    const float* Wd1 = (const float*)d_in[5];
    const float* bd1 = (const float*)d_in[6];
    const float* Wd2 = (const float*)d_in[7];
    const float* bd2 = (const float*)d_in[8];
    float* out = (float*)d_out;

    prep_w<<<32, 256, 0, stream>>>(Wg, Wd1, (__bf16*)d_ws);
    mt_fwd<<<4096, 128, 0, stream>>>(q, Win, bin, bg, bd1, Wd2, bd2,
                                     (const bf16x8*)d_ws, out);
}

// Round 9
// 310.679 us; speedup vs baseline: 1.9763x; 1.9763x over previous
//
#include <hip/hip_runtime.h>

// MicrotubuleDynamicsModel fused forward, round 9:
// Round-8 structure (feature-halved 16-plane LDS dbuf, deferred-update
// schedule, in-register D->B conversion via v_permlane32_swap_b32) with the
// launch bound corrected: (128,2) -> VGPR cap 128 (demand ~116), so no
// scratch spill, and occupancy 16 waves/CU (8 blocks x 13.8KB LDS).

typedef __attribute__((ext_vector_type(2)))  float  f32x2;
typedef __attribute__((ext_vector_type(4)))  float  f32x4;
typedef __attribute__((ext_vector_type(16))) float  f32x16;
typedef __attribute__((ext_vector_type(8)))  __bf16 bf16x8;
typedef __attribute__((ext_vector_type(4)))  unsigned int u32x4;

#define MFMA(a, b, c) __builtin_amdgcn_mfma_f32_32x32x16_bf16((a), (b), (c), 0, 0, 0)

#define QSTR 53          // node slots per quad-plane (52 + 1 pad)
#define QP   (QSTR * 4)  // dwords per quad-plane = 212

struct bfpair { __bf16 h, l; };
__device__ __forceinline__ bfpair splitf(float f) {
    bfpair p;
    p.h = (__bf16)f;               // RTN
    p.l = (__bf16)(f - (float)p.h);
    return p;
}
__device__ __forceinline__ unsigned pk2(__bf16 a, __bf16 b) {
    return (unsigned)__builtin_bit_cast(unsigned short, a)
         | ((unsigned)__builtin_bit_cast(unsigned short, b) << 16);
}

// D-layout k-chunk (regs RB..RB+7 of a 32x32 D tile) -> B-frag split pair.
// v_permlane32_swap_b32 exchanges (vdst's high 32 lanes) <-> (src's low 32
// lanes): (a0,b0) -> (word0, word2) for all lanes. Verified in round 8.
template<int RB>
__device__ __forceinline__ void d2b8(const f32x16 &v, bf16x8 &BH, bf16x8 &BL) {
    __bf16 h[8], l[8];
    #pragma unroll
    for (int i = 0; i < 8; ++i) { bfpair p = splitf(v[RB + i]); h[i] = p.h; l[i] = p.l; }
    unsigned ha0 = pk2(h[0], h[1]), ha1 = pk2(h[2], h[3]);
    unsigned hb0 = pk2(h[4], h[5]), hb1 = pk2(h[6], h[7]);
    unsigned la0 = pk2(l[0], l[1]), la1 = pk2(l[2], l[3]);
    unsigned lb0 = pk2(l[4], l[5]), lb1 = pk2(l[6], l[7]);
    asm("v_permlane32_swap_b32 %0, %1" : "+v"(ha0), "+v"(hb0));
    asm("v_permlane32_swap_b32 %0, %1" : "+v"(la0), "+v"(lb0));
    asm("v_permlane32_swap_b32 %0, %1" : "+v"(ha1), "+v"(hb1));
    asm("v_permlane32_swap_b32 %0, %1" : "+v"(la1), "+v"(lb1));
    u32x4 uh = { ha0, ha1, hb0, hb1 };
    u32x4 ul = { la0, la1, lb0, lb1 };
    BH = __builtin_bit_cast(bf16x8, uh);
    BL = __builtin_bit_cast(bf16x8, ul);
}

// ---------------- prep: split + fragment-pack W into workspace ----------------
// frag tid = (((L*8+kc)*4+ot)*2+hi)*32+lane ; elems = W[L][ot*32+lane][kc*16+hi*8+e]
__global__ __launch_bounds__(256) void prep_w(
    const float* __restrict__ Wg, const float* __restrict__ Wd1,
    __bf16* __restrict__ ws)
{
    const int tid  = blockIdx.x * 256 + threadIdx.x;   // 0..8191
    const int lane = tid & 31;
    const int hi   = (tid >> 5) & 1;
    const int ot   = (tid >> 6) & 3;
    const int kc   = (tid >> 8) & 7;
    const int L    = tid >> 11;
    const float* src = ((L < 3) ? (Wg + L * 16384) : Wd1)
                     + (ot * 32 + lane) * 128 + kc * 16 + hi * 8;
    const f32x4 v0 = *(const f32x4*)(src);
    const f32x4 v1 = *(const f32x4*)(src + 4);
    bf16x8 h8, l8;
    #pragma unroll
    for (int e = 0; e < 4; ++e) {
        bfpair p0 = splitf(v0[e]); h8[e]   = p0.h; l8[e]   = p0.l;
        bfpair p1 = splitf(v1[e]); h8[4+e] = p1.h; l8[4+e] = p1.l;
    }
    ((bf16x8*)ws)[tid]        = h8;   // Ph
    ((bf16x8*)ws)[8192 + tid] = l8;   // Pl
}

// ------------------------------- main kernel -------------------------------
__global__ __launch_bounds__(128, 2) void mt_fwd(
    const float* __restrict__ q,   const float* __restrict__ Win, const float* __restrict__ bin,
    const float* __restrict__ bg,  const float* __restrict__ bd1,
    const float* __restrict__ Wd2, const float* __restrict__ bd2,
    const bf16x8* __restrict__ Ph, float* __restrict__ out)
{
    __shared__ __attribute__((aligned(16))) float hb[16 * QP];   // 13568 B

    const int t    = threadIdx.x;
    const int nt   = t >> 6;            // wave: node-tile 0/1
    const int l    = t & 63;
    const int lane = l & 31;
    const int hi   = l >> 5;
    const int n    = nt * 32 + lane;    // this lane's node (col in D)
    const int nc   = (n < 52) ? n : 0;
    const int samp = blockIdx.x;
    const bf16x8* Pl = Ph + 8192;

    const int wq = n * 4;    // own node dword offset within a plane (write)
    const int rq = nc * 4;   // clamped (read own)

    // ---- closed-form GCN neighbors (self + 2 lateral(dup x2) + <=2 chain) ----
    int nb[5]; float nw[5];
    {
        const int   fi = n >> 2, js = n & 3;
        const float dg = 5.f + (js > 0 ? 1.f : 0.f) + (js < 3 ? 1.f : 0.f);
        const float di = rsqrtf(dg);
        nb[0] = n;                          nw[0] = di * di;
        nb[1] = ((fi + 12) % 13) * 4 + js;  nw[1] = 2.f * di * di;
        nb[2] = ((fi + 1) % 13) * 4 + js;   nw[2] = 2.f * di * di;
        nb[3] = (js > 0) ? (n - 1) : 0;
        nw[3] = (js > 0) ? di * rsqrtf(6.f + (js > 1 ? 1.f : 0.f)) : 0.f;
        nb[4] = (js < 3) ? (n + 1) : 0;
        nw[4] = (js < 3) ? di * rsqrtf(6.f + (js < 2 ? 1.f : 0.f)) : 0.f;
        if (n >= 52) {
            #pragma unroll
            for (int c = 0; c < 5; ++c) { nb[c] = 0; nw[c] = 0.f; }
        }
    }
    int gq[5];
    #pragma unroll
    for (int c = 0; c < 5; ++c) gq[c] = nb[c] * 4;

    bf16x8 bh[8], bl[8];   // persistent x state (B-frag layout, split)

    // ---------------- encoder: x0 = relu(Win @ q^T + bin), in-reg conversion ----------------
    {
        f32x4 z4; z4[0]=0.f; z4[1]=0.f; z4[2]=0.f; z4[3]=0.f;
        f32x4 u0 = z4, u1 = z4;
        if (hi == 0 && n < 52) {
            const float* qp = q + (samp * 52 + n) * 6;
            const f32x2 a = *(const f32x2*)(qp);
            const f32x2 b = *(const f32x2*)(qp + 2);
            const f32x2 c = *(const f32x2*)(qp + 4);
            u0[0]=a[0]; u0[1]=a[1]; u0[2]=b[0]; u0[3]=b[1]; u1[0]=c[0]; u1[1]=c[1];
        }
        bf16x8 qh, ql;
        #pragma unroll
        for (int e = 0; e < 4; ++e) {
            bfpair p0 = splitf(u0[e]); qh[e]   = p0.h; ql[e]   = p0.l;
            bfpair p1 = splitf(u1[e]); qh[4+e] = p1.h; ql[4+e] = p1.l;
        }

        #pragma unroll
        for (int ot = 0; ot < 4; ++ot) {
            f32x4 v0 = z4, v1 = z4;
            if (hi == 0) {
                const int o_r = ot * 32 + lane;
                const f32x2 a = *(const f32x2*)(Win + o_r * 6);
                const f32x2 b = *(const f32x2*)(Win + o_r * 6 + 2);
                const f32x2 c = *(const f32x2*)(Win + o_r * 6 + 4);
                v0[0]=a[0]; v0[1]=a[1]; v0[2]=b[0]; v0[3]=b[1]; v1[0]=c[0]; v1[1]=c[1];
            }
            bf16x8 ah, al;
            #pragma unroll
            for (int e = 0; e < 4; ++e) {
                bfpair p0 = splitf(v0[e]); ah[e]   = p0.h; al[e]   = p0.l;
                bfpair p1 = splitf(v1[e]); ah[4+e] = p1.h; al[4+e] = p1.l;
            }
            f32x16 acc;
            #pragma unroll
            for (int r = 0; r < 16; ++r) acc[r] = 0.f;
            acc = MFMA(ah, qh, acc);
            acc = MFMA(ah, ql, acc);
            acc = MFMA(al, qh, acc);
            // epilogue in regs
            f32x16 v;
            #pragma unroll
            for (int j = 0; j < 4; ++j) {
                const f32x4 bv = *(const f32x4*)(bin + ot * 32 + 8 * j + 4 * hi);
                #pragma unroll
                for (int e = 0; e < 4; ++e) v[4 * j + e] = fmaxf(acc[4 * j + e] + bv[e], 0.f);
            }
            d2b8<0>(v, bh[2 * ot],     bl[2 * ot]);
            d2b8<8>(v, bh[2 * ot + 1], bl[2 * ot + 1]);
        }
    }

    // helpers -----------------------------------------------------------------
    auto mmtile = [&](int fbase, int ot) {
        f32x16 acc;
        #pragma unroll
        for (int r = 0; r < 16; ++r) acc[r] = 0.f;
        #pragma unroll
        for (int kc = 0; kc < 8; ++kc) {
            const int fk = fbase + kc * 256 + ot * 64;
            const bf16x8 wh = Ph[fk];
            const bf16x8 wl = Pl[fk];
            acc = MFMA(wh, bh[kc], acc);
            acc = MFMA(wh, bl[kc], acc);
            acc = MFMA(wl, bh[kc], acc);
        }
        return acc;
    };
    auto wrplanes = [&](const f32x16 &acc, int ot) {
        if (n < 52) {
            #pragma unroll
            for (int j = 0; j < 4; ++j) {
                f32x4 v = { acc[4*j+0], acc[4*j+1], acc[4*j+2], acc[4*j+3] };
                *(f32x4*)&hb[((ot & 1) * 8 + 2 * j + hi) * QP + wq] = v;
            }
        }
    };
    auto wrplanesRelu = [&](const f32x16 &acc, int ot, const float* bsrc) {
        if (n < 52) {
            #pragma unroll
            for (int j = 0; j < 4; ++j) {
                const f32x4 bv = *(const f32x4*)(bsrc + ot * 32 + 8 * j + 4 * hi);
                f32x4 v;
                #pragma unroll
                for (int e = 0; e < 4; ++e) v[e] = fmaxf(acc[4 * j + e] + bv[e], 0.f);
                *(f32x4*)&hb[((ot & 1) * 8 + 2 * j + hi) * QP + wq] = v;
            }
        }
    };

    // ------------------- 3 GNN layers (deferred-update schedule) -------------------
    #pragma unroll 1
    for (int L = 0; L < 3; ++L) {
        const int fbase = L * 2048 + hi * 32 + lane;
        const float* bsrc = bg + L * 128;

        // mmA: ot 0,1 -> write planes
        {
            f32x16 a0 = mmtile(fbase, 0); wrplanes(a0, 0);
            f32x16 a1 = mmtile(fbase, 1); wrplanes(a1, 1);
        }
        __syncthreads();                         // bar1: half-A planes visible

        // mmB: ot 2,3 held in regs (old x fully consumed after this)
        f32x16 a2 = mmtile(fbase, 2);
        f32x16 a3 = mmtile(fbase, 3);

        // gatherA: kc 0..3, update state in place (old x dead)
        #pragma unroll
        for (int kc = 0; kc < 4; ++kc) {
            const int p0 = ((kc >> 1) & 1) * 8 + (kc & 1) * 4 + 2 * hi;
            f32x4 t0, t1;
            #pragma unroll
            for (int e = 0; e < 4; ++e) { t0[e] = 0.f; t1[e] = 0.f; }
            #pragma unroll
            for (int c = 0; c < 5; ++c) {
                t0 += nw[c] * *(const f32x4*)&hb[p0 * QP + gq[c]];
                t1 += nw[c] * *(const f32x4*)&hb[(p0 + 1) * QP + gq[c]];
            }
            const f32x4 b0 = *(const f32x4*)(bsrc + kc * 16 + 8 * hi);
            const f32x4 b1 = *(const f32x4*)(bsrc + kc * 16 + 8 * hi + 4);
            #pragma unroll
            for (int e = 0; e < 4; ++e) {
                {
                    const float xo = (float)bh[kc][e] + (float)bl[kc][e];
                    const float xn = xo + fmaxf(t0[e] + b0[e], 0.f);
                    bfpair p = splitf(xn); bh[kc][e] = p.h; bl[kc][e] = p.l;
                }
                {
                    const float xo = (float)bh[kc][4+e] + (float)bl[kc][4+e];
                    const float xn = xo + fmaxf(t1[e] + b1[e], 0.f);
                    bfpair p = splitf(xn); bh[kc][4+e] = p.h; bl[kc][4+e] = p.l;
                }
            }
        }
        __syncthreads();                         // bar2: gatherA reads done

        wrplanes(a2, 2);
        wrplanes(a3, 3);
        __syncthreads();                         // bar3: half-B planes visible

        // gatherB: kc 4..7
        #pragma unroll
        for (int kc = 4; kc < 8; ++kc) {
            const int p0 = ((kc >> 1) & 1) * 8 + (kc & 1) * 4 + 2 * hi;
            f32x4 t0, t1;
            #pragma unroll
            for (int e = 0; e < 4; ++e) { t0[e] = 0.f; t1[e] = 0.f; }
            #pragma unroll
            for (int c = 0; c < 5; ++c) {
                t0 += nw[c] * *(const f32x4*)&hb[p0 * QP + gq[c]];
                t1 += nw[c] * *(const f32x4*)&hb[(p0 + 1) * QP + gq[c]];
            }
            const f32x4 b0 = *(const f32x4*)(bsrc + kc * 16 + 8 * hi);
            const f32x4 b1 = *(const f32x4*)(bsrc + kc * 16 + 8 * hi + 4);
            #pragma unroll
            for (int e = 0; e < 4; ++e) {
                {
                    const float xo = (float)bh[kc][e] + (float)bl[kc][e];
                    const float xn = xo + fmaxf(t0[e] + b0[e], 0.f);
                    bfpair p = splitf(xn); bh[kc][e] = p.h; bl[kc][e] = p.l;
                }
                {
                    const float xo = (float)bh[kc][4+e] + (float)bl[kc][4+e];
                    const float xn = xo + fmaxf(t1[e] + b1[e], 0.f);
                    bfpair p = splitf(xn); bh[kc][4+e] = p.h; bl[kc][4+e] = p.l;
                }
            }
        }
        __syncthreads();                         // bar4: gatherB reads done
    }

    // ---------------- decoder-1: y = relu(x @ Wd1^T + bd1), parked halves ----------------
    {
        const int fbase = 3 * 2048 + hi * 32 + lane;
        {
            f32x16 a0 = mmtile(fbase, 0); wrplanesRelu(a0, 0, bd1);
            f32x16 a1 = mmtile(fbase, 1); wrplanesRelu(a1, 1, bd1);
        }
        __syncthreads();
        f32x16 a2 = mmtile(fbase, 2);
        f32x16 a3 = mmtile(fbase, 3);                // old x fully consumed
        // readback kc 0..3 (own node)
        #pragma unroll
        for (int kc = 0; kc < 4; ++kc) {
            const int p0 = ((kc >> 1) & 1) * 8 + (kc & 1) * 4 + 2 * hi;
            const f32x4 a0r = *(const f32x4*)&hb[p0 * QP + rq];
            const f32x4 a1r = *(const f32x4*)&hb[(p0 + 1) * QP + rq];
            #pragma unroll
            for (int e = 0; e < 4; ++e) {
                bfpair q0 = splitf(a0r[e]); bh[kc][e]   = q0.h; bl[kc][e]   = q0.l;
                bfpair q1 = splitf(a1r[e]); bh[kc][4+e] = q1.h; bl[kc][4+e] = q1.l;
            }
        }
        __syncthreads();
        wrplanesRelu(a2, 2, bd1);
        wrplanesRelu(a3, 3, bd1);
        __syncthreads();
        #pragma unroll
        for (int kc = 4; kc < 8; ++kc) {
            const int p0 = ((kc >> 1) & 1) * 8 + (kc & 1) * 4 + 2 * hi;
            const f32x4 a0r = *(const f32x4*)&hb[p0 * QP + rq];
            const f32x4 a1r = *(const f32x4*)&hb[(p0 + 1) * QP + rq];
            #pragma unroll
            for (int e = 0; e < 4; ++e) {
                bfpair q0 = splitf(a0r[e]); bh[kc][e]   = q0.h; bl[kc][e]   = q0.l;
                bfpair q1 = splitf(a1r[e]); bh[kc][4+e] = q1.h; bl[kc][4+e] = q1.l;
            }
        }
    }

    // ---------------- decoder-2: out^T = Wd2 @ y^T + bd2 ----------------
    {
        f32x16 acc;
        #pragma unroll
        for (int r = 0; r < 16; ++r) acc[r] = 0.f;
        f32x4 z4; z4[0]=0.f; z4[1]=0.f; z4[2]=0.f; z4[3]=0.f;

        #pragma unroll
        for (int kc = 0; kc < 8; ++kc) {
            const int kb = kc * 16 + 8 * hi;
            f32x4 w0 = z4, w1 = z4;
            if (lane < 6) {
                const float* wp = Wd2 + lane * 128 + kb;
                w0 = *(const f32x4*)(wp);
                w1 = *(const f32x4*)(wp + 4);
            }
            bf16x8 ah, al;
            #pragma unroll
            for (int e = 0; e < 4; ++e) {
                bfpair p0 = splitf(w0[e]); ah[e]   = p0.h; al[e]   = p0.l;
                bfpair p1 = splitf(w1[e]); ah[4+e] = p1.h; al[4+e] = p1.l;
            }
            acc = MFMA(ah, bh[kc], acc);
            acc = MFMA(ah, bl[kc], acc);
            acc = MFMA(al, bh[kc], acc);
        }
        if (n < 52) {
            float* op = out + (samp * 52 + n) * 6;
            if (hi == 0) {
                #pragma unroll
                for (int r = 0; r < 4; ++r) op[r] = acc[r] + bd2[r];          // f = r
            } else {
                #pragma unroll
                for (int r = 0; r < 2; ++r) op[4 + r] = acc[r] + bd2[4 + r];  // f = 4+r
            }
        }
    }
}

extern "C" void kernel_launch(void* const* d_in, const int* in_sizes, int n_in,
                              void* d_out, int out_size, void* d_ws, size_t ws_size,
                              hipStream_t stream) {
    (void)in_sizes; (void)n_in; (void)ws_size; (void)out_size;
    const float* q   = (const float*)d_in[0];
    const float* Win = (const float*)d_in[1];
    const float* bin = (const float*)d_in[2];
    const float* Wg  = (const float*)d_in[3];
    const float* bg  = (const float*)d_in[4];
    const float* Wd1 = (const float*)d_in[5];
    const float* bd1 = (const float*)d_in[6];
    const float* Wd2 = (const float*)d_in[7];
    const float* bd2 = (const float*)d_in[8];
    float* out = (float*)d_out;

    prep_w<<<32, 256, 0, stream>>>(Wg, Wd1, (__bf16*)d_ws);
    mt_fwd<<<4096, 128, 0, stream>>>(q, Win, bin, bg, bd1, Wd2, bd2,
                                     (const bf16x8*)d_ws, out);
}